// Round 9
// baseline (90.244 us; speedup 1.0000x reference)
//
#include <hip/hip_runtime.h>
#include <hip/hip_bf16.h>

#define N 8192
#define D 128
#define HALF_N 4096
// z pre-scaled by sqrt(10 * log2(e)) so acc = z.z^T is sim in log2 domain:
// exp(sim) == exp2(acc). pos (= sim) recovered as acc * ln2 on its single tile.
#define SQRT_SCALE_LOG2E 3.79828236f
#define LN2 0.693147180559945f

#define BLOCK_ROWS 256   // 4 waves * 64 rows each
#define COLS_PER_ITER 64
#define NCB 32           // 32 col-blocks of 256; upper triangle: by >= bx
#define COLS_PER_BLOCK 256
#define ITERS (COLS_PER_BLOCK / COLS_PER_ITER)   // 4

typedef short frag8 __attribute__((ext_vector_type(8)));
typedef float f32x4 __attribute__((ext_vector_type(4)));
typedef const __attribute__((address_space(1))) unsigned int* gbl_u32p;
typedef __attribute__((address_space(3))) unsigned int* lds_u32p;

// ws layout (floats): pos[N] | psumsR[32][N] | psumsC[32][N] | acc0 | pad | z (bf16)
// psumsR[k][i]: row-partials of tile (i>>8, k), k >= i>>8
// psumsC[k][i]: col-partials (mirrored rows) of tile (k, i>>8), k < i>>8
#define OFF_POS    0
#define OFF_PSR    (N)
#define OFF_PSC    (N + NCB * N)
#define OFF_ACC    (N + 2 * NCB * N)
#define OFF_Z_BYTES ((OFF_ACC + 64) * 4)

__device__ __forceinline__ unsigned short f2bf(float f) {
    unsigned int u = __float_as_uint(f);
    u += 0x7FFFu + ((u >> 16) & 1u);
    return (unsigned short)(u >> 16);
}

// K1: z = sqrt(10*log2e) * x / max(||x||, eps)  (bf16); zero scalar acc.
__global__ __launch_bounds__(256) void k_normalize(const float* __restrict__ x,
                                                   unsigned short* __restrict__ z,
                                                   float* __restrict__ acc0) {
    const int row  = blockIdx.x * 4 + (threadIdx.x >> 6);
    const int lane = threadIdx.x & 63;
    float2 v = ((const float2*)x)[row * 64 + lane];
    float s = v.x * v.x + v.y * v.y;
    #pragma unroll
    for (int m = 32; m >= 1; m >>= 1) s += __shfl_xor(s, m);
    float inv = SQRT_SCALE_LOG2E / fmaxf(sqrtf(s), 1e-8f);
    ushort2 o;
    o.x = f2bf(v.x * inv);
    o.y = f2bf(v.y * inv);
    ((ushort2*)z)[row * 64 + lane] = o;
    if (blockIdx.x == 0 && threadIdx.x == 0) acc0[0] = 0.0f;
}

// Stage one 64x128 bf16 tile into LDS via global_load_lds (linear dest,
// XOR-swizzled source so the ds_read side can swizzle conflict-free).
__device__ __forceinline__ void stage_tile(const unsigned short* __restrict__ z,
                                           unsigned short* ldsbuf,
                                           int colbase, int wave,
                                           const int* stg_src) {
    const unsigned short* zc = z + (size_t)colbase * D;
    #pragma unroll
    for (int u = 0; u < 4; ++u) {
        // wave-uniform LDS base; HW writes base + lane*16B (row = +lane>>4, chunk = lane&15)
        __builtin_amdgcn_global_load_lds((gbl_u32p)(zc + stg_src[u]),
                                         (lds_u32p)(ldsbuf + (wave * 16 + u * 4) * D),
                                         16, 0, 0);
    }
}

// K2: fused z.z^T + exp2 + partial sums, UPPER TRIANGLE ONLY (sim is symmetric).
// r2 proven core: LDS double-buffer, global_load_lds staged before compute,
// one __syncthreads per iter, 16x16x32 MFMA, #pragma unroll 1 (r6: full unroll
// at ITERS=4 -> VGPR 128 + 70MB spill). Rounds 3-8 showed per-tile cost is
// structure/TLP-insensitive -> halve the tiles: 528 of 1024 blocks do work.
// Off-diag tiles emit row-sums AND col-sums (mirrored rows); pos hits write
// both pos[i] and pos[i+4096] (symmetric pair).
__global__ __launch_bounds__(256, 2) void k_simloss(const unsigned short* __restrict__ z,
                                                    float* __restrict__ psumsR,
                                                    float* __restrict__ psumsC,
                                                    float* __restrict__ pos) {
    const int bx = blockIdx.x;   // row-block
    const int by = blockIdx.y;   // col-block
    if (by < bx) return;         // lower triangle: whole block exits (no barriers yet)

    __shared__ unsigned short lds[2][COLS_PER_ITER * D];  // 2 x 16 KB
    __shared__ float ldscol[4 * 256];                     // per-wave col-partials, 4 KB

    const int tid  = threadIdx.x;
    const int wave = tid >> 6;
    const int lane = tid & 63;
    const int l15  = lane & 15;
    const int quad = lane >> 4;
    const int l7   = l15 & 7;
    const int wrow = bx * BLOCK_ROWS + wave * 64;
    const int colbase0 = by * COLS_PER_BLOCK;
    const int posbase  = (wrow + HALF_N) & (N - 1);
    const bool diagBlk = (bx == by);

    // Staging source offsets: LDS slot (r, chunk'=l15) must hold global chunk (l15 ^ (r&7)).
    int stg_src[4];
    #pragma unroll
    for (int u = 0; u < 4; ++u) {
        int r = wave * 16 + u * 4 + (lane >> 4);
        stg_src[u] = r * D + ((l15 ^ (r & 7)) << 3);
    }

    // B-frag read offsets: data k-chunk (quad+4q) of row l15 sits at slot (quad+4q)^(l15&7).
    int boff[4];
    #pragma unroll
    for (int q = 0; q < 4; ++q)
        boff[q] = l15 * D + (((quad + 4 * q) ^ l7) << 3);

    // A fragments: 4 row-stripes of 16 x K=128, register-resident (64 VGPRs).
    frag8 a[4][4];
    #pragma unroll
    for (int s = 0; s < 4; ++s) {
        const uint4* p = (const uint4*)&z[(wrow + s * 16 + l15) * D + quad * 8];
        #pragma unroll
        for (int q = 0; q < 4; ++q) {
            uint4 t = p[q * 4];
            a[s][q] = *(frag8*)&t;
        }
    }

    float sums[4][4];
    #pragma unroll
    for (int s = 0; s < 4; ++s)
        #pragma unroll
        for (int r = 0; r < 4; ++r) sums[s][r] = 0.0f;

    stage_tile(z, &lds[0][0], colbase0, wave, stg_src);
    __syncthreads();  // drains vmcnt -> buf0 ready

    #pragma unroll 1
    for (int it = 0; it < ITERS; ++it) {
        // Issue next tile's loads NOW; they fly while we do MFMA+exp2 below.
        if (it + 1 < ITERS)
            stage_tile(z, &lds[(it + 1) & 1][0], colbase0 + (it + 1) * COLS_PER_ITER, wave, stg_src);

        const int colbase = colbase0 + it * COLS_PER_ITER;
        const bool isDiag = (colbase == wrow);
        const bool isPos  = (colbase == posbase);
        const unsigned short* lb = &lds[it & 1][0];

        float cs = 0.0f;  // this lane's col-sum for col (it*64 + quad*16 + l15)

        #pragma unroll
        for (int c = 0; c < 4; ++c) {
            f32x4 acc[4];
            #pragma unroll
            for (int s = 0; s < 4; ++s) acc[s] = (f32x4){0.f, 0.f, 0.f, 0.f};
            #pragma unroll
            for (int q = 0; q < 4; ++q) {
                frag8 b = *(const frag8*)&lb[c * (16 * D) + boff[q]];
                #pragma unroll
                for (int s = 0; s < 4; ++s)
                    acc[s] = __builtin_amdgcn_mfma_f32_16x16x32_bf16(a[s][q], b, acc[s], 0, 0, 0);
            }
            float cc = 0.0f;  // partial col-sum over this wave's 64 rows (16 in-lane)
            if (isDiag | isPos) {
                // special tile: local diagonal element at c==s, l15==quad*4+r
                #pragma unroll
                for (int s = 0; s < 4; ++s)
                    #pragma unroll
                    for (int r = 0; r < 4; ++r) {
                        float v = acc[s][r];
                        float e = __builtin_amdgcn_exp2f(v);
                        if (c == s) {  // compile-time
                            bool hit = (l15 == quad * 4 + r);
                            if (isDiag && hit) e = 0.0f;
                            if (isPos && hit) {
                                int row = wrow + s * 16 + quad * 4 + r;
                                float pv = v * LN2;
                                pos[row] = pv;
                                pos[row + HALF_N] = pv;  // symmetric pair (row<4096 here)
                            }
                        }
                        sums[s][r] += e;
                        cc += e;
                    }
            } else {
                #pragma unroll
                for (int s = 0; s < 4; ++s)
                    #pragma unroll
                    for (int r = 0; r < 4; ++r) {
                        float e = __builtin_amdgcn_exp2f(acc[s][r]);
                        sums[s][r] += e;
                        cc += e;
                    }
            }
            // reduce over quads (lanes differing in bits 4,5; l15 fixed): full 64-row colsum
            cc += __shfl_xor(cc, 16);
            cc += __shfl_xor(cc, 32);
            if (quad == c) cs = cc;  // c is compile-time; cs stays scalar (no dyn index)
        }
        // each lane owns one distinct col slot: it*64 + quad*16 + l15 (2-way banks = free)
        ldscol[wave * 256 + it * 64 + quad * 16 + l15] = cs;

        // One barrier per iter: ensures (a) next buf's global_load_lds landed,
        // (b) everyone is done reading buf[it&1] before it gets restaged next iter.
        __syncthreads();
    }

    // Row-sums: reduce across the 16 lanes holding that row; one store per row.
    #pragma unroll
    for (int s = 0; s < 4; ++s)
        #pragma unroll
        for (int r = 0; r < 4; ++r) {
            float v = sums[s][r];
            v += __shfl_xor(v, 1);
            v += __shfl_xor(v, 2);
            v += __shfl_xor(v, 4);
            v += __shfl_xor(v, 8);
            if (l15 == 0)
                psumsR[by * N + wrow + s * 16 + quad * 4 + r] = v;
        }

    // Col-sums (off-diag only; diag tile's col-partials == its row-partials,
    // counted once via psumsR). Last loop iter ended with __syncthreads ->
    // ldscol complete. 256 threads, one col each.
    if (!diagBlk) {
        float v = ldscol[tid] + ldscol[256 + tid] + ldscol[512 + tid] + ldscol[768 + tid];
        psumsC[bx * N + colbase0 + tid] = v;
    }
}

// K3a: row i total = sum of 32 partials: psumsR[k][i] for k>=R, psumsC[k][i] for k<R.
__global__ __launch_bounds__(256) void k_rowloss(const float* __restrict__ psumsR,
                                                 const float* __restrict__ psumsC,
                                                 const float* __restrict__ pos,
                                                 float* __restrict__ acc0) {
    const int row = blockIdx.x * 256 + threadIdx.x;
    const int R = row >> 8;
    float t = 0.0f;
    #pragma unroll
    for (int k = 0; k < NCB; ++k) {
        const float* p = (k >= R) ? psumsR : psumsC;
        t += p[k * N + row];
    }
    float loss = __logf(t) - pos[row];
    #pragma unroll
    for (int m = 32; m >= 1; m >>= 1) loss += __shfl_xor(loss, m);
    __shared__ float pp[4];
    if ((threadIdx.x & 63) == 0) pp[threadIdx.x >> 6] = loss;
    __syncthreads();
    if (threadIdx.x == 0)
        atomicAdd(acc0, pp[0] + pp[1] + pp[2] + pp[3]);
}

// K3b: mean.
__global__ void k_final(const float* __restrict__ acc0, float* __restrict__ out) {
    out[0] = acc0[0] * (1.0f / N);
}

extern "C" void kernel_launch(void* const* d_in, const int* in_sizes, int n_in,
                              void* d_out, int out_size, void* d_ws, size_t ws_size,
                              hipStream_t stream) {
    const float* x = (const float*)d_in[0];
    float* wsf    = (float*)d_ws;
    float* pos    = wsf + OFF_POS;
    float* psumsR = wsf + OFF_PSR;
    float* psumsC = wsf + OFF_PSC;
    float* acc0   = wsf + OFF_ACC;
    unsigned short* z = (unsigned short*)((char*)d_ws + OFF_Z_BYTES);

    k_normalize<<<N / 4, 256, 0, stream>>>(x, z, acc0);
    dim3 g2(N / BLOCK_ROWS, NCB);  // (32,32); by<bx exits -> 528 working blocks
    k_simloss<<<g2, 256, 0, stream>>>(z, psumsR, psumsC, pos);
    k_rowloss<<<N / 256, 256, 0, stream>>>(psumsR, psumsC, pos, acc0);
    k_final<<<1, 1, 0, stream>>>(acc0, (float*)d_out);
}

// Round 10
// 84.061 us; speedup vs baseline: 1.0736x; 1.0736x over previous
//
#include <hip/hip_runtime.h>
#include <hip/hip_bf16.h>

#define N 8192
#define D 128
#define HALF_N 4096
// z pre-scaled by sqrt(10 * log2(e)) so acc = z.z^T is sim in log2 domain:
// exp(sim) == exp2(acc). pos (= sim) recovered as acc * ln2 on its single tile.
#define SQRT_SCALE_LOG2E 3.79828236f
#define LN2 0.693147180559945f

#define BLOCK_ROWS 256   // 4 waves * 64 rows each
#define COLS_PER_ITER 64
#define COL_SPLITS 16
#define COLS_PER_BLOCK (N / COL_SPLITS)          // 512
#define ITERS (COLS_PER_BLOCK / COLS_PER_ITER)   // 8
#define NBUF 4           // 4-deep ring so the barrier can be vmcnt-counted:
                         // stage(t+2) stays in flight across the barrier.

typedef short frag8 __attribute__((ext_vector_type(8)));
typedef float f32x4 __attribute__((ext_vector_type(4)));
typedef const __attribute__((address_space(1))) unsigned int* gbl_u32p;
typedef __attribute__((address_space(3))) unsigned int* lds_u32p;

// ws layout (floats): pos[N] | psums[COL_SPLITS][N] | acc0 | pad | z (bf16)
#define OFF_POS    0
#define OFF_PSUMS  (N)
#define OFF_ACC    (N + COL_SPLITS * N)
#define OFF_Z_BYTES ((OFF_ACC + 64) * 4)

__device__ __forceinline__ unsigned short f2bf(float f) {
    unsigned int u = __float_as_uint(f);
    u += 0x7FFFu + ((u >> 16) & 1u);
    return (unsigned short)(u >> 16);
}

// K1: z = sqrt(10*log2e) * x / max(||x||, eps)  (bf16); zero scalar acc.
__global__ __launch_bounds__(256) void k_normalize(const float* __restrict__ x,
                                                   unsigned short* __restrict__ z,
                                                   float* __restrict__ acc0) {
    const int row  = blockIdx.x * 4 + (threadIdx.x >> 6);
    const int lane = threadIdx.x & 63;
    float2 v = ((const float2*)x)[row * 64 + lane];
    float s = v.x * v.x + v.y * v.y;
    #pragma unroll
    for (int m = 32; m >= 1; m >>= 1) s += __shfl_xor(s, m);
    float inv = SQRT_SCALE_LOG2E / fmaxf(sqrtf(s), 1e-8f);
    ushort2 o;
    o.x = f2bf(v.x * inv);
    o.y = f2bf(v.y * inv);
    ((ushort2*)z)[row * 64 + lane] = o;
    if (blockIdx.x == 0 && threadIdx.x == 0) acc0[0] = 0.0f;
}

// Stage one 64x128 bf16 tile into LDS via global_load_lds (linear dest,
// XOR-swizzled source so the ds_read side can swizzle conflict-free).
__device__ __forceinline__ void stage_tile(const unsigned short* __restrict__ z,
                                           unsigned short* ldsbuf,
                                           int colbase, int wave,
                                           const int* stg_src) {
    const unsigned short* zc = z + (size_t)colbase * D;
    #pragma unroll
    for (int u = 0; u < 4; ++u) {
        // wave-uniform LDS base; HW writes base + lane*16B (row = +lane>>4, chunk = lane&15)
        __builtin_amdgcn_global_load_lds((gbl_u32p)(zc + stg_src[u]),
                                         (lds_u32p)(ldsbuf + (wave * 16 + u * 4) * D),
                                         16, 0, 0);
    }
}

// Counted barrier (T4): all but the newest `vm` VMEM ops must have landed.
// "memory" clobber + sched_barrier(0) pin ds_reads below the barrier (rule #18).
#define CBAR(vm) do {                                        \
    asm volatile("s_waitcnt vmcnt(" #vm ")" ::: "memory");   \
    __builtin_amdgcn_s_barrier();                            \
    __builtin_amdgcn_sched_barrier(0);                       \
} while (0)

// K2: fused z.z^T + exp2 + per-row partial sums.
// r2 proven core (82.0 us) with ONE isolated change: the per-iter __syncthreads
// (which drains vmcnt to 0, exposing the just-issued stage's full L2 round trip
// to ALL 8 waves of the CU -- m97's documented ~20% stall, and the only
// structural stall rounds 3-9 never isolated) is replaced by the T4 pattern:
// 4-buffer ring, stage t+2 issued at iter top, s_waitcnt vmcnt(4) + s_barrier.
// vmcnt is oldest-first (m135): the newest 4 = stage(t+2) (+ later pos stores),
// so vmcnt(4) proves stage(t+1) landed while stage(t+2) stays in flight.
// Ring-safety: barrier skew <= 1 iter; writer buf[(t+3)&3] never aliases
// reader buf[(t+1)&3]. #pragma unroll 1 pins codegen (r6 spill trap).
__global__ __launch_bounds__(256, 2) void k_simloss(const unsigned short* __restrict__ z,
                                                    float* __restrict__ psums,
                                                    float* __restrict__ pos) {
    __shared__ unsigned short lds[NBUF][COLS_PER_ITER * D];  // 4 x 16 KB = 64 KB

    const int tid  = threadIdx.x;
    const int wave = tid >> 6;
    const int lane = tid & 63;
    const int l15  = lane & 15;
    const int quad = lane >> 4;
    const int l7   = l15 & 7;
    const int wrow = blockIdx.x * BLOCK_ROWS + wave * 64;
    const int colbase0 = blockIdx.y * COLS_PER_BLOCK;
    const int posbase  = (wrow + HALF_N) & (N - 1);

    // Staging source offsets: LDS slot (r, chunk'=l15) must hold global chunk (l15 ^ (r&7)).
    int stg_src[4];
    #pragma unroll
    for (int u = 0; u < 4; ++u) {
        int r = wave * 16 + u * 4 + (lane >> 4);
        stg_src[u] = r * D + ((l15 ^ (r & 7)) << 3);
    }

    // B-frag read offsets: data k-chunk (quad+4q) of row l15 sits at slot (quad+4q)^(l15&7).
    int boff[4];
    #pragma unroll
    for (int q = 0; q < 4; ++q)
        boff[q] = l15 * D + (((quad + 4 * q) ^ l7) << 3);

    // A fragments: 4 row-stripes of 16 x K=128, register-resident (64 VGPRs).
    frag8 a[4][4];
    #pragma unroll
    for (int s = 0; s < 4; ++s) {
        const uint4* p = (const uint4*)&z[(wrow + s * 16 + l15) * D + quad * 8];
        #pragma unroll
        for (int q = 0; q < 4; ++q) {
            uint4 t = p[q * 4];
            a[s][q] = *(frag8*)&t;
        }
    }

    float sums[4][4];
    #pragma unroll
    for (int s = 0; s < 4; ++s)
        #pragma unroll
        for (int r = 0; r < 4; ++r) sums[s][r] = 0.0f;

    // Prologue: stage tiles 0 and 1; wait for tile 0 only (newest 4 = stage 1).
    stage_tile(z, &lds[0][0], colbase0 + 0 * COLS_PER_ITER, wave, stg_src);
    stage_tile(z, &lds[1][0], colbase0 + 1 * COLS_PER_ITER, wave, stg_src);
    CBAR(4);

    #pragma unroll 1
    for (int it = 0; it < ITERS; ++it) {
        // Issue stage(t+2) NOW; it stays in flight across this iter's barrier.
        if (it + 2 < ITERS)
            stage_tile(z, &lds[(it + 2) & 3][0], colbase0 + (it + 2) * COLS_PER_ITER, wave, stg_src);

        const int colbase = colbase0 + it * COLS_PER_ITER;
        const bool isDiag = (colbase == wrow);
        const bool isPos  = (colbase == posbase);
        const unsigned short* lb = &lds[it & 3][0];

        #pragma unroll
        for (int c = 0; c < 4; ++c) {
            f32x4 acc[4];
            #pragma unroll
            for (int s = 0; s < 4; ++s) acc[s] = (f32x4){0.f, 0.f, 0.f, 0.f};
            #pragma unroll
            for (int q = 0; q < 4; ++q) {
                frag8 b = *(const frag8*)&lb[c * (16 * D) + boff[q]];
                #pragma unroll
                for (int s = 0; s < 4; ++s)
                    acc[s] = __builtin_amdgcn_mfma_f32_16x16x32_bf16(a[s][q], b, acc[s], 0, 0, 0);
            }
            if (isDiag | isPos) {
                // special tile: local diagonal element at c==s, l15==quad*4+r
                #pragma unroll
                for (int s = 0; s < 4; ++s)
                    #pragma unroll
                    for (int r = 0; r < 4; ++r) {
                        float v = acc[s][r];
                        float e = __builtin_amdgcn_exp2f(v);
                        if (c == s) {  // compile-time
                            bool hit = (l15 == quad * 4 + r);
                            if (isDiag && hit) e = 0.0f;
                            if (isPos  && hit) pos[wrow + s * 16 + quad * 4 + r] = v * LN2;
                        }
                        sums[s][r] += e;
                    }
            } else {
                #pragma unroll
                for (int s = 0; s < 4; ++s)
                    #pragma unroll
                    for (int r = 0; r < 4; ++r)
                        sums[s][r] += __builtin_amdgcn_exp2f(acc[s][r]);
            }
        }

        // Counted barrier: stage(t+1) proven landed; stage(t+2) stays in flight.
        if (it < ITERS - 2)       CBAR(4);
        else if (it == ITERS - 2) CBAR(0);   // last stage (tile 7) must land
        // it == ITERS-1: no barrier; epilogue only touches regs + global.
    }

    // Reduce each row-sum across the 16 lanes holding that row; one store per row.
    #pragma unroll
    for (int s = 0; s < 4; ++s)
        #pragma unroll
        for (int r = 0; r < 4; ++r) {
            float v = sums[s][r];
            v += __shfl_xor(v, 1);
            v += __shfl_xor(v, 2);
            v += __shfl_xor(v, 4);
            v += __shfl_xor(v, 8);
            if (l15 == 0)
                psums[blockIdx.y * N + wrow + s * 16 + quad * 4 + r] = v;
        }
}

// K3a: per-row loss = log(sum of partials) - pos; block-reduce; atomic into acc0.
__global__ __launch_bounds__(1024) void k_rowloss(const float* __restrict__ psums,
                                                  const float* __restrict__ pos,
                                                  float* __restrict__ acc0) {
    const int row = blockIdx.x * 1024 + threadIdx.x;
    float t = 0.0f;
    #pragma unroll
    for (int s = 0; s < COL_SPLITS; ++s) t += psums[s * N + row];
    float loss = __logf(t) - pos[row];
    #pragma unroll
    for (int m = 32; m >= 1; m >>= 1) loss += __shfl_xor(loss, m);
    __shared__ float p[16];
    if ((threadIdx.x & 63) == 0) p[threadIdx.x >> 6] = loss;
    __syncthreads();
    if (threadIdx.x == 0) {
        float s = 0.0f;
        #pragma unroll
        for (int w = 0; w < 16; ++w) s += p[w];
        atomicAdd(acc0, s);
    }
}

// K3b: mean.
__global__ void k_final(const float* __restrict__ acc0, float* __restrict__ out) {
    out[0] = acc0[0] * (1.0f / N);
}

extern "C" void kernel_launch(void* const* d_in, const int* in_sizes, int n_in,
                              void* d_out, int out_size, void* d_ws, size_t ws_size,
                              hipStream_t stream) {
    const float* x = (const float*)d_in[0];
    float* wsf   = (float*)d_ws;
    float* pos   = wsf + OFF_POS;
    float* psums = wsf + OFF_PSUMS;
    float* acc0  = wsf + OFF_ACC;
    unsigned short* z = (unsigned short*)((char*)d_ws + OFF_Z_BYTES);

    k_normalize<<<N / 4, 256, 0, stream>>>(x, z, acc0);
    dim3 g2(N / BLOCK_ROWS, COL_SPLITS);  // (32, 16) = 512 blocks -> 2/CU
    k_simloss<<<g2, 256, 0, stream>>>(z, psums, pos);
    k_rowloss<<<N / 1024, 1024, 0, stream>>>(psums, pos, acc0);
    k_final<<<1, 1, 0, stream>>>(acc0, (float*)d_out);
}